// Round 1
// baseline (763.710 us; speedup 1.0000x reference)
//
#include <hip/hip_runtime.h>
#include <cfloat>
#include <cstdint>

#define EMB_DIM 1024
#define NKEYS   65536
#define TOPK    512
#define BATCH   128
#define NBINS   4096   // 12-bit bins of monotone fp32 key
#define CAP     2048   // candidate buffer (expected ~870 with this data)

// ---------------------------------------------------------------------------
// Kernel A: sims[n] = dot(keys[n], query) / max(||keys[n]||, eps)
// (division by q_norm skipped: common positive factor, order-preserving)
// One wave (64 lanes) per row; f64 accumulation for rank stability.
// ---------------------------------------------------------------------------
__global__ __launch_bounds__(256) void sims_kernel(
    const float* __restrict__ keys, const float* __restrict__ query,
    double* __restrict__ sims)
{
    const int wave = threadIdx.x >> 6;
    const int lane = threadIdx.x & 63;
    const int row  = blockIdx.x * 4 + wave;

    const float4* __restrict__ krow = (const float4*)(keys + (size_t)row * EMB_DIM);
    const float4* __restrict__ q4   = (const float4*)query;

    double dot = 0.0, ss = 0.0;
#pragma unroll
    for (int j = 0; j < 4; ++j) {
        const int c = lane + 64 * j;          // 256 float4s per row
        float4 kv = krow[c];
        float4 qv = q4[c];
        dot += (double)kv.x * qv.x + (double)kv.y * qv.y +
               (double)kv.z * qv.z + (double)kv.w * qv.w;
        ss  += (double)kv.x * kv.x + (double)kv.y * kv.y +
               (double)kv.z * kv.z + (double)kv.w * kv.w;
    }
#pragma unroll
    for (int off = 32; off > 0; off >>= 1) {
        dot += __shfl_xor(dot, off);
        ss  += __shfl_xor(ss, off);
    }
    if (lane == 0) {
        double norm = sqrt(ss);
        if (norm < 1e-8) norm = 1e-8;
        sims[row] = dot / norm;
    }
}

// ---------------------------------------------------------------------------
// Kernel B: exact top-K (descending sim, ties -> lower index), single block.
// Histogram-select on top-12 bits of monotone fp32 key, then LDS bitonic sort
// of the ~K+bin candidates by full f64 value.
// ---------------------------------------------------------------------------
__device__ __forceinline__ unsigned mono32(float f) {
    unsigned u = __float_as_uint(f);
    return (u & 0x80000000u) ? ~u : (u | 0x80000000u);
}

__global__ __launch_bounds__(1024) void topk_kernel(
    const double* __restrict__ sims, int* __restrict__ topk)
{
    __shared__ int    hist[NBINS];
    __shared__ int    sfx[NBINS];
    __shared__ double cs[CAP];
    __shared__ int    ci[CAP];
    __shared__ int    bstar_s;
    __shared__ int    cnt;

    const int tid = threadIdx.x;

    for (int i = tid; i < NBINS; i += 1024) hist[i] = 0;
    if (tid == 0) cnt = 0;
    __syncthreads();

    // Phase 1: histogram of top-12 monotone-key bits
    for (int n = tid; n < NKEYS; n += 1024) {
        unsigned b = mono32((float)sims[n]) >> 20;   // 32-12 = 20
        atomicAdd(&hist[b], 1);
    }
    __syncthreads();

    // Phase 2: suffix sums (Hillis-Steele, ping-pong hist<->sfx)
    int* src = hist;
    int* dst = sfx;
    for (int off = 1; off < NBINS; off <<= 1) {
        for (int i = tid; i < NBINS; i += 1024) {
            int v = src[i];
            if (i + off < NBINS) v += src[i + off];
            dst[i] = v;
        }
        __syncthreads();
        int* t = src; src = dst; dst = t;
    }
    // src[i] = count of elements with bin >= i. Find largest b with src[b] >= K.
    for (int i = tid; i < NBINS; i += 1024) {
        if (src[i] >= TOPK && (i == NBINS - 1 || src[i + 1] < TOPK)) bstar_s = i;
    }
    __syncthreads();
    const int bstar = bstar_s;

    // Phase 3: collect candidates (all elements with bin >= bstar)
    for (int n = tid; n < NKEYS; n += 1024) {
        double s = sims[n];
        unsigned b = mono32((float)s) >> 20;
        if ((int)b >= bstar) {
            int pos = atomicAdd(&cnt, 1);
            if (pos < CAP) { cs[pos] = s; ci[pos] = n; }
        }
    }
    __syncthreads();

    int c = cnt; if (c > CAP) c = CAP;
    for (int i = tid; i < CAP; i += 1024) {
        if (i >= c) { cs[i] = -DBL_MAX; ci[i] = 0x7fffffff; }
    }
    __syncthreads();

    // Phase 4: bitonic sort, "ascending" order == (sim desc, idx asc)
    for (int k = 2; k <= CAP; k <<= 1) {
        for (int j = k >> 1; j > 0; j >>= 1) {
            for (int i = tid; i < CAP; i += 1024) {
                int ixj = i ^ j;
                if (ixj > i) {
                    double s1 = cs[i], s2 = cs[ixj];
                    int    i1 = ci[i], i2 = ci[ixj];
                    // elem[i] should come AFTER elem[ixj] in desired order?
                    bool a_after_b = (s1 < s2) || (s1 == s2 && i1 > i2);
                    bool up = ((i & k) == 0);
                    if (up ? a_after_b : !a_after_b) {
                        cs[i] = s2; ci[i] = i2;
                        cs[ixj] = s1; ci[ixj] = i1;
                    }
                }
            }
            __syncthreads();
        }
    }

    if (tid < TOPK) topk[tid] = ci[tid];
}

// ---------------------------------------------------------------------------
// Kernel C: out[b,k,:] = x[b,k,:] + prompts[topk[k],:]
// blockIdx = k*B + b so 128 consecutive blocks share one prompt row (L2 hit).
// ---------------------------------------------------------------------------
__global__ __launch_bounds__(256) void add_kernel(
    const float* __restrict__ x, const float* __restrict__ prompts,
    const int* __restrict__ topk, float* __restrict__ out)
{
    const int b = blockIdx.x & (BATCH - 1);
    const int k = blockIdx.x >> 7;
    const int idx = topk[k];

    const size_t row = ((size_t)b * TOPK + k) * (EMB_DIM / 4);
    const float4* __restrict__ xr = (const float4*)x + row;
    const float4* __restrict__ pr = (const float4*)prompts + (size_t)idx * (EMB_DIM / 4);
    float4* __restrict__ outr = (float4*)out + row;

    const int t = threadIdx.x;
    float4 xv = xr[t];
    float4 pv = pr[t];
    outr[t] = make_float4(xv.x + pv.x, xv.y + pv.y, xv.z + pv.z, xv.w + pv.w);
}

// ---------------------------------------------------------------------------
extern "C" void kernel_launch(void* const* d_in, const int* in_sizes, int n_in,
                              void* d_out, int out_size, void* d_ws, size_t ws_size,
                              hipStream_t stream)
{
    const float* x       = (const float*)d_in[0];
    const float* query   = (const float*)d_in[1];
    const float* keys    = (const float*)d_in[2];
    const float* prompts = (const float*)d_in[3];

    double* sims = (double*)d_ws;                                  // 512 KB
    int*    topk = (int*)((char*)d_ws + NKEYS * sizeof(double));   // 2 KB

    sims_kernel<<<NKEYS / 4, 256, 0, stream>>>(keys, query, sims);
    topk_kernel<<<1, 1024, 0, stream>>>(sims, topk);
    add_kernel<<<BATCH * TOPK, 256, 0, stream>>>(x, prompts, topk, (float*)d_out);
}